// Round 13
// baseline (95.467 us; speedup 1.0000x reference)
//
#include <hip/hip_runtime.h>
#include <math.h>

// PostProcess: B=16, Q=2048, C=2. R13 = R12 (95.1us, passing) + two
// scheduling-only changes (no semantic surface):
//  1. SOFTWARE-PIPELINED SCAN: A/B register double-buffer; chunk c+1's 16
//     r16-loads + diag-load issue BEFORE processing chunk c, so the pop chain
//     never waits on ds_read (~120-150cy/chunk hidden). 2x-unrolled loop,
//     zero register copies (R10's prefetch cost was the 64-op copy), all
//     static indexing (rule #20). Address formulas verbatim R12.
//  2. BALANCED PRODUCER MAPPING: gi = slice + 16*wave (+256k) -- bijective
//     remap of the verified round-robin. Old slice-major mapping gave slice 0
//     (the consumer!) row-block 0 = widest rows (144 word-units vs 45 avg);
//     balanced drops the critical path ~3x and the consumer reaches its spin
//     earlier. Same gi set covered; rbase depends only on gi, not slice.
// ws: flags u32[256]@0 | mat u32[16][17408]@1024  (1,115,136 B < proven 1.148MB)

#define QN     2048
#define NS     1024      // fast-path max valid boxes (E[M]=562, sd~20; M>NS ~23 sigma)
#define NSLICE 16
#define MATW   17408     // ragged u32 words/image = 64 * sum_{wb<16}(32-2wb)
#define MAGIC  0x5ca1ab1eu

__device__ __forceinline__ int rb32(int wb) { return 64 * wb * (33 - wb); }

__device__ __forceinline__ unsigned long long shfl_xor_u64(unsigned long long x, int m) {
    int lo = __shfl_xor((int)(unsigned)(x & 0xffffffffull), m, 64);
    int hi = __shfl_xor((int)(unsigned)(x >> 32), m, 64);
    return ((unsigned long long)(unsigned)hi << 32) | (unsigned)lo;
}

// ascending key order == score desc, idx asc (stable); invalid -> tail.
__device__ __forceinline__ unsigned long long score_key(float2 l, int q, bool* valid_out) {
    float mx = fmaxf(l.x, l.y), mn = fminf(l.x, l.y);
    float e = expf(mn - mx);
    float score = 1.0f / (1.0f + e);                 // max softmax prob (exact ref order)
    bool valid = (l.x >= l.y) && (score >= 0.7f);    // argmax tie -> class 0
    *valid_out = valid;
    unsigned sbits = valid ? __float_as_uint(score) : 0u;
    return ((unsigned long long)(~sbits) << 32) | (unsigned)q;
}

// scan helpers: load chunk c into (RBUF, DIAG); process chunk c from them.
// Address formulas verbatim R12 (verified).
#define SCAN_LOAD(RBUF, DIAG, c) do {                                         \
    const int wb_ = (c) >> 1, rl_ = 32 - 2 * wb_;                             \
    const int half_ = ((c) & 1) << 5;                                         \
    const int Lc_ = min(max((int)(tid & 31), 2 * wb_), 31);                   \
    const int rb0_ = rb32(wb_) + half_ * rl_ + (Lc_ - 2 * wb_);               \
    _Pragma("unroll")                                                         \
    for (int t = 0; t < 16; ++t) RBUF[t] = gm[rb0_ + (tb + t) * rl_];         \
    DIAG = gm[rb32(wb_) + (half_ + lam) * rl_ + ((c) - 2 * wb_)];             \
} while (0)

#define SCAN_PROC(RBUF, DIAG, c) do {                                         \
    int lim_ = min(32, Ms - ((c) << 5));                                      \
    unsigned limmask_ = (lim_ >= 32) ? 0xFFFFFFFFu : ((1u << lim_) - 1u);     \
    unsigned rw_ = ((unsigned)__builtin_amdgcn_readlane((int)rem, (c)))       \
                   | ~limmask_;                                               \
    unsigned keepmask_ = 0;                                                   \
    _Pragma("unroll")                                                         \
    for (int t = 0; t < 32; ++t) {                                            \
        unsigned keep_ = ((~rw_) >> t) & 1u;                                  \
        unsigned rword_ = (unsigned)__builtin_amdgcn_readlane((int)(DIAG), t);\
        rw_ |= (0u - keep_) & rword_;                                         \
        keepmask_ |= keep_ << t;                                              \
    }                                                                         \
    unsigned part_ = 0;                                                       \
    _Pragma("unroll")                                                         \
    for (int t = 0; t < 16; ++t)                                              \
        part_ |= (0u - ((keepmask_ >> (tb + t)) & 1u)) & RBUF[t];             \
    part_ |= (unsigned)__shfl_xor((int)part_, 32, 64);                        \
    rem |= part_;                                                             \
    if (tid == 0) skm[(c)] = keepmask_;                                       \
} while (0)

__global__ __launch_bounds__(1024) void kfused(
    const float* __restrict__ logits, const float* __restrict__ pboxes,
    const int* __restrict__ img_h_p, const int* __restrict__ img_w_p,
    unsigned* __restrict__ wflag, unsigned* __restrict__ wmat,
    float* __restrict__ out, int B)
{
    // producer: skey u64[NS]@0 | sx1@8192 sy1@12288 sx2@16384 sy2@20480
    //           sar@24576 | sidxl u16[NS]@28672 | sM@32896 | skeyB u64[NS]@33024
    // consumer: skm u32[32]@33024 (skeyB dead after sort) | smat u32[MATW]@41216
    // fallback overlays @0: skeyF u64[QN] (16KB) | ssupp@16384 | keepqF@18432
    __shared__ __align__(16) char smem[110848];
    unsigned long long* skey = (unsigned long long*)smem;
    float* sx1 = (float*)(smem + 8192);
    float* sy1 = (float*)(smem + 12288);
    float* sx2 = (float*)(smem + 16384);
    float* sy2 = (float*)(smem + 20480);
    float* sar = (float*)(smem + 24576);
    unsigned short* sidxl = (unsigned short*)(smem + 28672);
    int* sMp = (int*)(smem + 32896);
    unsigned long long* skeyB = (unsigned long long*)(smem + 33024);
    unsigned* skm = (unsigned*)(smem + 33024);
    unsigned* smat = (unsigned*)(smem + 41216);

    const int blk = blockIdx.x;
    const int b = blk % B, slice = blk / B;
    const int tid = threadIdx.x, lane = tid & 63, wave = tid >> 6;
    const float sw = (float)(*img_w_p), sh = (float)(*img_h_p);
    const long BQ = (long)B * QN;

    if (tid == 0) *sMp = 0;
    __syncthreads();

    // ---- compact valid keys (ballot compaction; verified R4-R12) ----
    const unsigned long long lmask_lt = (1ull << lane) - 1ull;
#pragma unroll
    for (int qq = 0; qq < 2; ++qq) {
        int q = tid + qq * 1024;
        float2 l = ((const float2*)logits)[b * QN + q];
        bool valid;
        unsigned long long key = score_key(l, q, &valid);
        unsigned long long mb = __ballot(valid);
        int base = 0;
        if (lane == 0 && mb) base = atomicAdd(sMp, __popcll(mb));
        base = __shfl(base, 0, 64);
        if (valid) {
            int slot = base + __popcll(mb & lmask_lt);
            if (slot < NS) skey[slot] = key;
        }
    }
    __syncthreads();
    const int M = *sMp;

    if (M <= NS) {
        // ---- register bitonic sort of NS u64, 1 elem/thread (verified R4/R5) ----
        unsigned long long v = (tid < M) ? skey[tid] : ~0ull;
        __syncthreads();   // skey reused as exchange buffer
#pragma unroll
        for (int k = 2; k <= 64; k <<= 1) {
            bool dir = ((tid & k) == 0);
#pragma unroll
            for (int j = k >> 1; j > 0; j >>= 1) {
                unsigned long long o = shfl_xor_u64(v, j);
                bool takeMin = (dir == ((tid & j) == 0));
                v = ((v < o) == takeMin) ? v : o;
            }
        }
        int pp = 0;
        for (int k = 128; k <= NS; k <<= 1) {
            bool dir = ((tid & k) == 0);
            for (int j = k >> 1; j >= 64; j >>= 1) {
                unsigned long long* buf = pp ? skeyB : skey;
                pp ^= 1;
                buf[tid] = v;
                __syncthreads();
                unsigned long long o = buf[tid ^ j];
                bool takeMin = (dir == ((tid & j) == 0));
                v = ((v < o) == takeMin) ? v : o;
            }
#pragma unroll
            for (int j = 32; j > 0; j >>= 1) {
                unsigned long long o = shfl_xor_u64(v, j);
                bool takeMin = (dir == ((tid & j) == 0));
                v = ((v < o) == takeMin) ? v : o;
            }
        }
        // sorted SoA (padding slots zero -> iou 0)
        int qi = (int)((unsigned)v & 0xffffu);
        sidxl[tid] = (unsigned short)qi;
        float x1 = 0.f, y1 = 0.f, x2 = 0.f, y2 = 0.f, ar = 0.f;
        if (tid < M) {
            float4 pb = ((const float4*)pboxes)[b * QN + qi];
            x1 = (pb.x - 0.5f * pb.z) * sw;
            y1 = (pb.y - 0.5f * pb.w) * sh;
            x2 = (pb.x + 0.5f * pb.z) * sw;
            y2 = (pb.y + 0.5f * pb.w) * sh;
            ar = fmaxf(x2 - x1, 0.f) * fmaxf(y2 - y1, 0.f);
        }
        sx1[tid] = x1; sy1[tid] = y1; sx2[tid] = x2; sy2[tid] = y2; sar[tid] = ar;
        __syncthreads();

        // ---- matrix slice (verified body R5-R12; BALANCED gi mapping) ----
        unsigned* mat = wmat + (long)b * MATW;
        const int NG = (M + 3) >> 2;
        const int W64 = (M + 63) >> 6;
        for (int gi = slice + 16 * wave; gi < NG; gi += 256) {
            const int g = gi << 2;
            const int nr = min(4, M - g);
            const int wb = g >> 6;
            const int rl = 32 - 2 * wb;
            float ax1[4], ay1[4], ax2[4], ay2[4], aar[4];
            int rbase[4];
#pragma unroll
            for (int r = 0; r < 4; ++r) {
                int i = g + min(r, nr - 1);
                ax1[r] = sx1[i]; ay1[r] = sy1[i];
                ax2[r] = sx2[i]; ay2[r] = sy2[i]; aar[r] = sar[i];
                rbase[r] = rb32(wb) + ((g + r) & 63) * rl;
            }
            for (int w = wb; w < W64; ++w) {
                int j = (w << 6) | lane;
                float bx1 = sx1[j], by1 = sy1[j], bx2 = sx2[j], by2 = sy2[j], bar = sar[j];
#pragma unroll
                for (int r = 0; r < 4; ++r) {
                    float ltx = fmaxf(ax1[r], bx1), lty = fmaxf(ay1[r], by1);
                    float rbx = fminf(ax2[r], bx2), rby = fminf(ay2[r], by2);
                    float wx = fmaxf(rbx - ltx, 0.f), wy = fmaxf(rby - lty, 0.f);
                    float inter = wx * wy;
                    float uni = aar[r] + bar - inter;       // exact ref op order
                    float iou = inter / fmaxf(uni, 1e-9f);  // exact IEEE div
                    bool sup = (iou > 0.5f) && (j > g + r);
                    unsigned long long bal = __ballot(sup);
                    if (lane == 0 && r < nr)
                        *(unsigned long long*)(mat + rbase[r] + 2 * (w - wb)) = bal;
                }
            }
        }
    }

    // ---- inverted epilogue part 1: zero-write this slice's 128-q stripe ----
    if (tid < 128) {
        int q = slice * 128 + tid;
        int base = b * QN + q;
        out[base] = 0.f;
        out[BQ * 5 + base] = 0.f;
        float4 z; z.x = 0.f; z.y = 0.f; z.z = 0.f; z.w = 0.f;
        ((float4*)(out + BQ))[base] = z;
    }

    __syncthreads();   // drains matrix + zero stores (vmcnt 0 at barrier)
    if (tid == 0)
        __hip_atomic_store(&wflag[b * NSLICE + slice], MAGIC,
                           __ATOMIC_RELEASE, __HIP_MEMORY_SCOPE_AGENT);
    if (slice != 0) return;    // producers done; consumer block continues

    // ---- consumer: spin for all 16 slices (verified R5/R11 MAGIC scheme) ----
    if (wave == 0) {
        const unsigned* fp = &wflag[b * NSLICE + (lane & (NSLICE - 1))];
        for (;;) {
            unsigned f = (lane < NSLICE)
                ? __hip_atomic_load(fp, __ATOMIC_ACQUIRE, __HIP_MEMORY_SCOPE_AGENT)
                : MAGIC;
            if (__all(f == MAGIC)) break;
            __builtin_amdgcn_s_sleep(2);
        }
    }
    __syncthreads();   // all 16 waves held until flags acquired

    if (M <= NS) {
        // ---- stage matrix (vec4 coalesced) into LDS (verified R9-R12) ----
        const int W64 = (M + 63) >> 6;
        const int nw4 = rb32(W64) >> 2;          // rb32 is divisible by 4
        const uint4* gm4 = (const uint4*)(wmat + (long)b * MATW);
        uint4* sm4 = (uint4*)smat;
        for (int i = tid; i < nw4; i += 1024) sm4[i] = gm4[i];
        __syncthreads();

        // ---- single-wave scan, software-pipelined A/B double-buffer ----
        if (tid < 64) {
            const unsigned* gm = smat;
            unsigned rem = 0;
            const int Ms = __builtin_amdgcn_readfirstlane(M);
            const int C = (Ms + 31) >> 5;
            const int lam = min(tid, 31);
            const int tb = (tid >> 5) << 4;      // rows [0,16) / [16,32) per half
            unsigned rA[16], rB[16], diagA = 0, diagB = 0;
            if (C > 0) SCAN_LOAD(rA, diagA, 0);
            for (int c = 0; c < C; c += 2) {
                if (c + 1 < C) SCAN_LOAD(rB, diagB, c + 1);   // prefetch
                SCAN_PROC(rA, diagA, c);
                if (c + 1 < C) {
                    if (c + 2 < C) SCAN_LOAD(rA, diagA, c + 2);  // prefetch
                    SCAN_PROC(rB, diagB, c + 1);
                }
            }
        }
        __syncthreads();

        // ---- inverted epilogue part 2: write ONLY kept entries (verified R11) ----
        for (int s = tid; s < M; s += 1024) {
            if ((skm[s >> 5] >> (s & 31)) & 1u) {
                int qi = sidxl[s];
                int base = b * QN + qi;
                float2 l = ((const float2*)logits)[base];
                float e = expf(fminf(l.x, l.y) - fmaxf(l.x, l.y));
                float score = 1.0f / (1.0f + e);
                float4 pb = ((const float4*)pboxes)[base];
                float x1 = (pb.x - 0.5f * pb.z) * sw, y1 = (pb.y - 0.5f * pb.w) * sh;
                float x2 = (pb.x + 0.5f * pb.z) * sw, y2 = (pb.y + 0.5f * pb.w) * sh;
                out[base] = score;
                out[BQ * 5 + base] = 1.f;
                float4 ob;
                ob.x = truncf(x1); ob.y = truncf(y1);
                ob.z = truncf(x2); ob.w = truncf(y2);
                ((float4*)(out + BQ))[base] = ob;
            }
        }
    } else {
        // ---- Fallback (M > NS, ~never): self-contained sort + greedy + full
        //      epilogue (overwrites producers' zeros; ordered by acquire) ----
        unsigned long long* skeyF = (unsigned long long*)smem;
        unsigned char* ssupp = (unsigned char*)(smem + 16384);
        unsigned char* keepqF = (unsigned char*)(smem + 18432);
        for (int qq = tid; qq < QN; qq += 1024) {
            float2 l = ((const float2*)logits)[b * QN + qq];
            bool valid;
            skeyF[qq] = score_key(l, qq, &valid);
        }
        keepqF[tid] = 0; keepqF[tid + 1024] = 0;
        __syncthreads();
        for (int k = 2; k <= QN; k <<= 1)
            for (int j = k >> 1; j > 0; j >>= 1) {
                int i = ((tid & ~(j - 1)) << 1) | (tid & (j - 1));
                int p = i | j;
                bool up = ((i & k) == 0);
                unsigned long long a = skeyF[i], c2 = skeyF[p];
                if ((a > c2) == up) { skeyF[i] = c2; skeyF[p] = a; }
                __syncthreads();
            }
        for (int s = tid; s < M; s += 1024) ssupp[s] = 0;
        __syncthreads();
        for (int i = 0; i < M; ++i) {
            __syncthreads();
            if (ssupp[i]) continue;
            int ia = (unsigned short)(unsigned)skeyF[i];
            float4 pa = ((const float4*)pboxes)[b * QN + ia];
            float ax1 = (pa.x - 0.5f * pa.z) * sw, ay1 = (pa.y - 0.5f * pa.w) * sh;
            float ax2 = (pa.x + 0.5f * pa.z) * sw, ay2 = (pa.y + 0.5f * pa.w) * sh;
            float areaA = fmaxf(ax2 - ax1, 0.f) * fmaxf(ay2 - ay1, 0.f);
            for (int jj = i + 1 + tid; jj < M; jj += 1024) {
                int jb = (unsigned short)(unsigned)skeyF[jj];
                float4 pq = ((const float4*)pboxes)[b * QN + jb];
                float bx1 = (pq.x - 0.5f * pq.z) * sw, by1 = (pq.y - 0.5f * pq.w) * sh;
                float bx2 = (pq.x + 0.5f * pq.z) * sw, by2 = (pq.y + 0.5f * pq.w) * sh;
                float ltx = fmaxf(ax1, bx1), lty = fmaxf(ay1, by1);
                float rbx = fminf(ax2, bx2), rby = fminf(ay2, by2);
                float wx = fmaxf(rbx - ltx, 0.f), wy = fmaxf(rby - lty, 0.f);
                float inter = wx * wy;
                float areaB = fmaxf(bx2 - bx1, 0.f) * fmaxf(by2 - by1, 0.f);
                float uni = areaA + areaB - inter;
                if (inter / fmaxf(uni, 1e-9f) > 0.5f) ssupp[jj] = 1;
            }
        }
        __syncthreads();
        for (int s = tid; s < M; s += 1024)
            if (!ssupp[s]) keepqF[(unsigned short)(unsigned)skeyF[s]] = 1;
        __syncthreads();
#pragma unroll
        for (int qq = 0; qq < 2; ++qq) {
            int q = tid + qq * 1024;
            int base = b * QN + q;
            float2 l = ((const float2*)logits)[base];
            float e = expf(fminf(l.x, l.y) - fmaxf(l.x, l.y));
            float score = 1.0f / (1.0f + e);
            float4 pb = ((const float4*)pboxes)[base];
            float x1 = (pb.x - 0.5f * pb.z) * sw, y1 = (pb.y - 0.5f * pb.w) * sh;
            float x2 = (pb.x + 0.5f * pb.z) * sw, y2 = (pb.y + 0.5f * pb.w) * sh;
            int kp = keepqF[q];
            out[base] = kp ? score : 0.f;
            out[BQ * 5 + base] = kp ? 1.f : 0.f;
            float4 ob;
            ob.x = kp ? truncf(x1) : 0.f;
            ob.y = kp ? truncf(y1) : 0.f;
            ob.z = kp ? truncf(x2) : 0.f;
            ob.w = kp ? truncf(y2) : 0.f;
            ((float4*)(out + BQ))[base] = ob;
        }
    }
}

extern "C" void kernel_launch(void* const* d_in, const int* in_sizes, int n_in,
                              void* d_out, int out_size, void* d_ws, size_t ws_size,
                              hipStream_t stream) {
    const float* logits = (const float*)d_in[0];
    const float* pboxes = (const float*)d_in[1];
    const int*   img_h  = (const int*)d_in[2];
    const int*   img_w  = (const int*)d_in[3];
    float* out = (float*)d_out;
    const int B = in_sizes[0] / (QN * 2);   // 16

    char* ws = (char*)d_ws;                 // footprint 1,115,136 B (< proven 1.148MB)
    unsigned* wflag = (unsigned*)(ws + 0);
    unsigned* wmat  = (unsigned*)(ws + 1024);

    kfused<<<dim3(B * NSLICE), dim3(1024), 0, stream>>>(logits, pboxes, img_h, img_w,
                                                        wflag, wmat, out, B);
}